// Round 9
// baseline (487.678 us; speedup 1.0000x reference)
//
#include <hip/hip_runtime.h>

#define B_ 128
#define T_ 256
#define H_ 768
#define K_ 64
#define BT_ (B_ * T_)

// ---------------------------------------------------------------------------
// DPP helpers: wave-wide max in ~6 VALU ops (row_shr/bcast ladder).
// ---------------------------------------------------------------------------
template <int CTRL>
__device__ __forceinline__ float dpp_mov_f(float x) {
    return __int_as_float(__builtin_amdgcn_update_dpp(
        __float_as_int(x), __float_as_int(x), CTRL, 0xF, 0xF, false));
}
__device__ __forceinline__ float wave_max64(float x) {
    x = fmaxf(x, dpp_mov_f<0x111>(x));  // row_shr:1
    x = fmaxf(x, dpp_mov_f<0x112>(x));  // row_shr:2
    x = fmaxf(x, dpp_mov_f<0x114>(x));  // row_shr:4
    x = fmaxf(x, dpp_mov_f<0x118>(x));  // row_shr:8
    x = fmaxf(x, dpp_mov_f<0x142>(x));  // row_bcast:15
    x = fmaxf(x, dpp_mov_f<0x143>(x));  // row_bcast:31
    return __int_as_float(__builtin_amdgcn_readlane(__float_as_int(x), 63));
}
__device__ __forceinline__ float readlane0_f(float x) {
    return __int_as_float(__builtin_amdgcn_readfirstlane(__float_as_int(x)));
}
template <int I>
__device__ __forceinline__ float readlane_f(float x) {
    return __int_as_float(__builtin_amdgcn_readlane(__float_as_int(x), I));
}

// ---------------------------------------------------------------------------
// Kernel A: emissions = hidden @ W + b.  (round-2 version; not the lever.)
// ---------------------------------------------------------------------------
#define BK_ 32
#define BM_ 64
#define P_ 66
__global__ __launch_bounds__(256) void gemm_emis(const float* __restrict__ hidden,
                                                 const float* __restrict__ W,
                                                 const float* __restrict__ bias,
                                                 float* __restrict__ emis) {
    __shared__ float At[BK_ * P_];

    const int tid = threadIdx.x;
    const int lane = tid & 63;
    const int wc = __builtin_amdgcn_readfirstlane((tid >> 6) * 16);
    const int rowbase = blockIdx.x * BM_;
    const int srow = tid >> 2;
    const int scol = (tid & 3) * 8;

    float acc[16];
#pragma unroll
    for (int c = 0; c < 16; ++c) acc[c] = bias[wc + c];

    float4 pf0 = *(const float4*)&hidden[(size_t)(rowbase + srow) * H_ + scol];
    float4 pf1 = *(const float4*)&hidden[(size_t)(rowbase + srow) * H_ + scol + 4];

    for (int kb = 0; kb < H_ / BK_; ++kb) {
        __syncthreads();
        At[(scol + 0) * P_ + srow] = pf0.x;
        At[(scol + 1) * P_ + srow] = pf0.y;
        At[(scol + 2) * P_ + srow] = pf0.z;
        At[(scol + 3) * P_ + srow] = pf0.w;
        At[(scol + 4) * P_ + srow] = pf1.x;
        At[(scol + 5) * P_ + srow] = pf1.y;
        At[(scol + 6) * P_ + srow] = pf1.z;
        At[(scol + 7) * P_ + srow] = pf1.w;
        __syncthreads();
        if (kb + 1 < H_ / BK_) {
            pf0 = *(const float4*)&hidden[(size_t)(rowbase + srow) * H_ +
                                          (kb + 1) * BK_ + scol];
            pf1 = *(const float4*)&hidden[(size_t)(rowbase + srow) * H_ +
                                          (kb + 1) * BK_ + scol + 4];
        }
        const float* Wk = &W[(kb * BK_) * K_ + wc];
#pragma unroll 8
        for (int h = 0; h < BK_; ++h) {
            float a = At[h * P_ + lane];
            float4 w0 = *(const float4*)&Wk[h * K_ + 0];
            float4 w1 = *(const float4*)&Wk[h * K_ + 4];
            float4 w2 = *(const float4*)&Wk[h * K_ + 8];
            float4 w3 = *(const float4*)&Wk[h * K_ + 12];
            acc[0]  += a * w0.x;  acc[1]  += a * w0.y;
            acc[2]  += a * w0.z;  acc[3]  += a * w0.w;
            acc[4]  += a * w1.x;  acc[5]  += a * w1.y;
            acc[6]  += a * w1.z;  acc[7]  += a * w1.w;
            acc[8]  += a * w2.x;  acc[9]  += a * w2.y;
            acc[10] += a * w2.z;  acc[11] += a * w2.w;
            acc[12] += a * w3.x;  acc[13] += a * w3.y;
            acc[14] += a * w3.z;  acc[15] += a * w3.w;
        }
    }

    float* e = &emis[(size_t)(rowbase + lane) * K_ + wc];
#pragma unroll
    for (int q = 0; q < 4; ++q)
        *(float4*)&e[q * 4] = make_float4(acc[q * 4], acc[q * 4 + 1],
                                          acc[q * 4 + 2], acc[q * 4 + 3]);
}

// ---------------------------------------------------------------------------
// Kernel B: fused CRF.  Round 9: TLP — 4 independent batches per 512-thread
// block (8 waves; SIMD k hosts fwd-wave of batch k + vit-wave of batch k,
// no barriers). Evidence r0-r8: every structure runs at ~1330cy/step with
// 1 wave/SIMD and VALUBusy 10-17% — per-wave wait-states no intra-wave
// restructuring can cover. Co-resident independent waves are the one untried
// axis. LDS cut 145KB -> 64KB to allow 8 waves: (a) emissions via 2-step-
// ahead global prefetch (L2-resident, ~200cy << step time); (b) Viterbi
// v-history replaced by in-scan BACKPOINTERS (1B/state/step): argmax tracked
// ascending-i with strict '>' in 4 blocks of 16 merged in order -> first-max
// = np.argmax tie rule (same rule as the passing ballot code); backtrack is
// 255 serial LDS byte reads. Forward wave = r0 code verbatim (global e).
// ---------------------------------------------------------------------------
__global__ __launch_bounds__(512, 1) void crf_kernel(const float* __restrict__ emis,
                                                     const int* __restrict__ masks,
                                                     const int* __restrict__ target,
                                                     const float* __restrict__ trans,
                                                     float* __restrict__ out) {
    __shared__ unsigned char bpbuf[4][T_][K_];   // 64 KB backpointers (4 batches)

    const int tid = threadIdx.x;
    const int lane = tid & 63;
    const int wv = tid >> 6;         // 0..7
    const int bq = wv & 3;           // batch slot in block
    const int role = wv >> 2;        // 0 = forward, 1 = viterbi
    const int b = blockIdx.x * 4 + bq;
    const float* eg = emis + (size_t)b * (T_ * K_);

    int sl = 0;
#pragma unroll
    for (int k = 0; k < 4; ++k) sl += masks[b * T_ + lane + k * 64];
#pragma unroll
    for (int m = 32; m; m >>= 1) sl += __shfl_xor(sl, m, 64);
    const int seq_len = sl;

    if (role == 0) {
        // ================= forward, delayed normalization ===================
        float Ecol[64];
#pragma unroll
        for (int i = 0; i < 64; ++i) Ecol[i] = __expf(trans[i * K_ + lane]);

        float e_c = eg[lane];                 // row 0
        float e00 = readlane0_f(e_c);
        float p = __expf(e_c - e00);          // e^{alpha_0} = p * e^C
        float C = e00;
        float logD0prev = 0.f;
        float eN1 = eg[K_ + lane];            // row 1
        float en0 = readlane0_f(eN1);
        float xg = __expf(eN1 - en0);         // x * g  (row 1)
        float eP = eg[2 * K_ + lane];         // row 2 (prefetched, 1-iter lead)

        for (int t = 1; t < T_; ++t) {
            float eQ = (t <= T_ - 3) ? eg[(t + 2) * K_ + lane] : 0.f;  // row t+2
            float a0 = 0.f, a1 = 0.f, a2 = 0.f, a3 = 0.f;
            float a4 = 0.f, a5 = 0.f, a6 = 0.f, a7 = 0.f;
#define FWD8(base)                                                     \
            a0 = fmaf(readlane_f<base + 0>(p), Ecol[base + 0], a0);    \
            a1 = fmaf(readlane_f<base + 1>(p), Ecol[base + 1], a1);    \
            a2 = fmaf(readlane_f<base + 2>(p), Ecol[base + 2], a2);    \
            a3 = fmaf(readlane_f<base + 3>(p), Ecol[base + 3], a3);    \
            a4 = fmaf(readlane_f<base + 4>(p), Ecol[base + 4], a4);    \
            a5 = fmaf(readlane_f<base + 5>(p), Ecol[base + 5], a5);    \
            a6 = fmaf(readlane_f<base + 6>(p), Ecol[base + 6], a6);    \
            a7 = fmaf(readlane_f<base + 7>(p), Ecol[base + 7], a7);
            FWD8(0) FWD8(8) FWD8(16) FWD8(24) FWD8(32) FWD8(40) FWD8(48) FWD8(56)
#undef FWD8
            float D = ((a0 + a1) + (a2 + a3)) + ((a4 + a5) + (a6 + a7));
            float pnew = D * xg;              // only on-chain op after the dot
            if (t < seq_len) { p = pnew; C += en0 + logD0prev; }
            // off-chain prep for next step (consumes eP = row t+1)
            float D0 = readlane0_f(D);
            logD0prev = __logf(D0);
            float gn = __fdividef(1.f, D0);
            en0 = readlane0_f(eP);
            xg = __expf(eP - en0) * gn;
            eP = eQ;
        }
        float rs = p;
#pragma unroll
        for (int m = 32; m; m >>= 1) rs += __shfl_xor(rs, m, 64);
        float log_norm = C + __logf(rs);

        // ---------------- sequence score (global gather) ----------------
        float sc = 0.f;
#pragma unroll
        for (int k = 0; k < 4; ++k) {
            int t = lane + k * 64;
            if (t < seq_len) {
                int tg = target[b * T_ + t];
                sc += eg[t * K_ + tg];
                if (t >= 1) sc += trans[target[b * T_ + t - 1] * K_ + tg];
            }
        }
#pragma unroll
        for (int m = 32; m; m >>= 1) sc += __shfl_xor(sc, m, 64);
        if (lane == 0) out[BT_ + b] = sc - log_norm;
    } else {
        // ================= Viterbi: max-plus with in-scan backpointers ======
        float Tcol[64];
#pragma unroll
        for (int i = 0; i < 64; ++i) Tcol[i] = trans[i * K_ + lane];

        float v = eg[lane];                   // row 0
        float eU = eg[K_ + lane];             // row 1 (used at t=1)
        float eP = eg[2 * K_ + lane];         // row 2

        for (int t = 1; t < T_; ++t) {
            float eQ = (t <= T_ - 3) ? eg[(t + 2) * K_ + lane] : 0.f;
            // 4 ascending chains of 16 (strict '>' keeps FIRST max in chain;
            // in-order merge keeps lowest chain on ties -> np.argmax rule)
            float m0 = readlane_f<0>(v)  + Tcol[0];  int i0 = 0;
            float m1 = readlane_f<16>(v) + Tcol[16]; int i1 = 16;
            float m2 = readlane_f<32>(v) + Tcol[32]; int i2 = 32;
            float m3 = readlane_f<48>(v) + Tcol[48]; int i3 = 48;
#define CAND(c, k)                                                         \
            { float s_ = readlane_f<(c)*16 + (k)>(v) + Tcol[(c)*16 + (k)]; \
              bool g_ = s_ > m##c;                                         \
              m##c = g_ ? s_ : m##c;                                       \
              i##c = g_ ? ((c)*16 + (k)) : i##c; }
#define CAND4(k) CAND(0, k) CAND(1, k) CAND(2, k) CAND(3, k)
            CAND4(1)  CAND4(2)  CAND4(3)  CAND4(4)  CAND4(5)
            CAND4(6)  CAND4(7)  CAND4(8)  CAND4(9)  CAND4(10)
            CAND4(11) CAND4(12) CAND4(13) CAND4(14) CAND4(15)
#undef CAND4
#undef CAND
            bool g01 = m1 > m0;
            float mA = g01 ? m1 : m0;  int iA = g01 ? i1 : i0;
            bool g23 = m3 > m2;
            float mB = g23 ? m3 : m2;  int iB = g23 ? i3 : i2;
            bool gAB = mB > mA;
            float M  = gAB ? mB : mA;  int iF = gAB ? iB : iA;

            float vn = M + eU;
            if (t < seq_len) v = vn;
            bpbuf[bq][t][lane] = (unsigned char)iF;   // off-chain byte write
            eU = eP; eP = eQ;
        }

        // last tag: first index of max over lanes (np.argmax tie rule)
        float M = wave_max64(v);
        unsigned long long ball = __ballot(v >= M);
        int tag = (int)__builtin_ctzll(ball);

        int path[4];
#pragma unroll
        for (int k = 0; k < 4; ++k) path[k] = 0;
        if (lane == ((T_ - 1) & 63)) path[(T_ - 1) >> 6] = tag;

        for (int t = T_ - 1; t >= 1; --t) {
            if (t < seq_len) tag = (int)bpbuf[bq][t][tag];  // serial byte read
            int pidx = t - 1;
            if (lane == (pidx & 63)) path[pidx >> 6] = tag;
        }
#pragma unroll
        for (int k = 0; k < 4; ++k) {
            int t = lane + k * 64;
            out[b * T_ + t] = (t < seq_len) ? (float)path[k] : 0.f;
        }
    }
}

// ---------------------------------------------------------------------------
extern "C" void kernel_launch(void* const* d_in, const int* in_sizes, int n_in,
                              void* d_out, int out_size, void* d_ws, size_t ws_size,
                              hipStream_t stream) {
    const float* hidden = (const float*)d_in[0];
    const int* masks    = (const int*)d_in[1];
    const int* target   = (const int*)d_in[2];
    const float* W      = (const float*)d_in[3];
    const float* bias   = (const float*)d_in[4];
    const float* trans  = (const float*)d_in[5];
    float* out = (float*)d_out;
    float* emis = (float*)d_ws;

    gemm_emis<<<dim3(BT_ / BM_), dim3(256), 0, stream>>>(hidden, W, bias, emis);
    crf_kernel<<<dim3(B_ / 4), dim3(512), 0, stream>>>(emis, masks, target, trans, out);
}

// Round 10
// 358.728 us; speedup vs baseline: 1.3595x; 1.3595x over previous
//
#include <hip/hip_runtime.h>

#define B_ 128
#define T_ 256
#define H_ 768
#define K_ 64
#define BT_ (B_ * T_)

// ---------------------------------------------------------------------------
// DPP helpers: wave-wide max in ~6 VALU ops (row_shr/bcast ladder).
// ---------------------------------------------------------------------------
template <int CTRL>
__device__ __forceinline__ float dpp_mov_f(float x) {
    return __int_as_float(__builtin_amdgcn_update_dpp(
        __float_as_int(x), __float_as_int(x), CTRL, 0xF, 0xF, false));
}
__device__ __forceinline__ float wave_max64(float x) {
    x = fmaxf(x, dpp_mov_f<0x111>(x));  // row_shr:1
    x = fmaxf(x, dpp_mov_f<0x112>(x));  // row_shr:2
    x = fmaxf(x, dpp_mov_f<0x114>(x));  // row_shr:4
    x = fmaxf(x, dpp_mov_f<0x118>(x));  // row_shr:8
    x = fmaxf(x, dpp_mov_f<0x142>(x));  // row_bcast:15
    x = fmaxf(x, dpp_mov_f<0x143>(x));  // row_bcast:31
    return __int_as_float(__builtin_amdgcn_readlane(__float_as_int(x), 63));
}
__device__ __forceinline__ float readlane0_f(float x) {
    return __int_as_float(__builtin_amdgcn_readfirstlane(__float_as_int(x)));
}

// ---------------------------------------------------------------------------
// Packed fp32 (VOP3P, CDNA2+): 2 fp32 ops per instruction.
// ---------------------------------------------------------------------------
__device__ __forceinline__ float2 pk_fma2(float2 a, float2 b, float2 c) {
    float2 d;
    asm("v_pk_fma_f32 %0, %1, %2, %3" : "=v"(d) : "v"(a), "v"(b), "v"(c));
    return d;
}
__device__ __forceinline__ float2 pk_add2(float2 a, float2 b) {
    float2 d;
    asm("v_pk_add_f32 %0, %1, %2" : "=v"(d) : "v"(a), "v"(b));
    return d;
}

// ---------------------------------------------------------------------------
// Kernel A: emissions = hidden @ W + b.  (round-2 version; not the lever.)
// ---------------------------------------------------------------------------
#define BK_ 32
#define BM_ 64
#define P_ 66
__global__ __launch_bounds__(256) void gemm_emis(const float* __restrict__ hidden,
                                                 const float* __restrict__ W,
                                                 const float* __restrict__ bias,
                                                 float* __restrict__ emis) {
    __shared__ float At[BK_ * P_];

    const int tid = threadIdx.x;
    const int lane = tid & 63;
    const int wc = __builtin_amdgcn_readfirstlane((tid >> 6) * 16);
    const int rowbase = blockIdx.x * BM_;
    const int srow = tid >> 2;
    const int scol = (tid & 3) * 8;

    float acc[16];
#pragma unroll
    for (int c = 0; c < 16; ++c) acc[c] = bias[wc + c];

    float4 pf0 = *(const float4*)&hidden[(size_t)(rowbase + srow) * H_ + scol];
    float4 pf1 = *(const float4*)&hidden[(size_t)(rowbase + srow) * H_ + scol + 4];

    for (int kb = 0; kb < H_ / BK_; ++kb) {
        __syncthreads();
        At[(scol + 0) * P_ + srow] = pf0.x;
        At[(scol + 1) * P_ + srow] = pf0.y;
        At[(scol + 2) * P_ + srow] = pf0.z;
        At[(scol + 3) * P_ + srow] = pf0.w;
        At[(scol + 4) * P_ + srow] = pf1.x;
        At[(scol + 5) * P_ + srow] = pf1.y;
        At[(scol + 6) * P_ + srow] = pf1.z;
        At[(scol + 7) * P_ + srow] = pf1.w;
        __syncthreads();
        if (kb + 1 < H_ / BK_) {
            pf0 = *(const float4*)&hidden[(size_t)(rowbase + srow) * H_ +
                                          (kb + 1) * BK_ + scol];
            pf1 = *(const float4*)&hidden[(size_t)(rowbase + srow) * H_ +
                                          (kb + 1) * BK_ + scol + 4];
        }
        const float* Wk = &W[(kb * BK_) * K_ + wc];
#pragma unroll 8
        for (int h = 0; h < BK_; ++h) {
            float a = At[h * P_ + lane];
            float4 w0 = *(const float4*)&Wk[h * K_ + 0];
            float4 w1 = *(const float4*)&Wk[h * K_ + 4];
            float4 w2 = *(const float4*)&Wk[h * K_ + 8];
            float4 w3 = *(const float4*)&Wk[h * K_ + 12];
            acc[0]  += a * w0.x;  acc[1]  += a * w0.y;
            acc[2]  += a * w0.z;  acc[3]  += a * w0.w;
            acc[4]  += a * w1.x;  acc[5]  += a * w1.y;
            acc[6]  += a * w1.z;  acc[7]  += a * w1.w;
            acc[8]  += a * w2.x;  acc[9]  += a * w2.y;
            acc[10] += a * w2.z;  acc[11] += a * w2.w;
            acc[12] += a * w3.x;  acc[13] += a * w3.y;
            acc[14] += a * w3.z;  acc[15] += a * w3.w;
        }
    }

    float* e = &emis[(size_t)(rowbase + lane) * K_ + wc];
#pragma unroll
    for (int q = 0; q < 4; ++q)
        *(float4*)&e[q * 4] = make_float4(acc[q * 4], acc[q * 4 + 1],
                                          acc[q * 4 + 2], acc[q * 4 + 3]);
}

// ---------------------------------------------------------------------------
// Kernel B: fused CRF.  Round 10: PACKED-FP32 cores on the r8 pipelined
// skeleton. Evidence: r1 (2x ops -> 2x time) + r9 (2 waves/SIMD serialize at
// ~76% active-SIMD VALUBusy) => per-SIMD VALU issue is the saturated
// resource; time ~ emitted op count. This round halves the core op count:
// all 64 exchange values arrive as 32 float2 LDS reads (pipelined one step
// ahead, r8-proven write->read ordering, no barrier); forward dot = 32
// v_pk_fma_f32 + 3 v_pk_add_f32; viterbi = 32 v_pk_add_f32 (exact scalar
// adds per half) + 32 v_max3_f32 reading pair halves directly. Zero
// readlanes in the loop. Viterbi max-set identical -> bit-exact decode;
// forward dot regrouped only (r4-r8 precedent, absmax 0.0).
// ---------------------------------------------------------------------------
__global__ __launch_bounds__(128, 1) void crf_kernel(const float* __restrict__ emis,
                                                     const int* __restrict__ masks,
                                                     const int* __restrict__ target,
                                                     const float* __restrict__ trans,
                                                     float* __restrict__ out) {
    __shared__ __align__(16) float ebuf[T_ * K_];   // 64 KB emissions for batch b
    __shared__ __align__(16) float vbuf[T_ * K_];   // 64 KB viterbi v-history
    __shared__ float tbuf[K_ * 65];                 // padded trans rows (backtrack)
    __shared__ __align__(16) float pexch[K_];       // forward p exchange vector

    const int tid = threadIdx.x;
    const int lane = tid & 63;
    const int b = blockIdx.x;
    const float* eb = emis + (size_t)b * (T_ * K_);

    // stage emissions: 4096 float4s over 128 threads
    {
        const float4* src = (const float4*)eb;
        float4* dst = (float4*)ebuf;
#pragma unroll
        for (int k = 0; k < 32; ++k) dst[tid + k * 128] = src[tid + k * 128];
    }
    int sl = 0;
#pragma unroll
    for (int k = 0; k < 4; ++k) sl += masks[b * T_ + lane + k * 64];
#pragma unroll
    for (int m = 32; m; m >>= 1) sl += __shfl_xor(sl, m, 64);
    const int seq_len = sl;
    __syncthreads();

    if (tid < 64) {
        // ================= forward (wave 0), delayed normalization ==========
        // Ep[k] = (exp(trans[2k][lane]), exp(trans[2k+1][lane]))
        float2 Ep[32];
#pragma unroll
        for (int k = 0; k < 32; ++k)
            Ep[k] = make_float2(__expf(trans[(2 * k) * K_ + lane]),
                                __expf(trans[(2 * k + 1) * K_ + lane]));

        float e_c = ebuf[lane];
        float e00 = readlane0_f(e_c);
        float p = __expf(e_c - e00);     // e^{alpha_0} = p * e^C
        float C = e00;
        float logD0prev = 0.f;
        float e_n = ebuf[K_ + lane];
        float en0 = readlane0_f(e_n);
        float xg = __expf(e_n - en0);    // x * g

        // publish p_0 and pre-issue the step-1 exchange reads (float2 pairs)
        pexch[lane] = p;
        float2 Lp[32];
#pragma unroll
        for (int k = 0; k < 32; ++k) Lp[k] = *(const float2*)&pexch[2 * k];

        for (int t = 1; t < T_; ++t) {
            float e_f = (t < T_ - 1) ? ebuf[(t + 1) * K_ + lane] : 0.f;
            float2 a0 = make_float2(0.f, 0.f), a1 = a0, a2 = a0, a3 = a0;
#pragma unroll
            for (int k = 0; k < 32; k += 4) {
                a0 = pk_fma2(Lp[k + 0], Ep[k + 0], a0);
                a1 = pk_fma2(Lp[k + 1], Ep[k + 1], a1);
                a2 = pk_fma2(Lp[k + 2], Ep[k + 2], a2);
                a3 = pk_fma2(Lp[k + 3], Ep[k + 3], a3);
            }
            a0 = pk_add2(a0, a1);
            a2 = pk_add2(a2, a3);
            a0 = pk_add2(a0, a2);
            float D = a0.x + a0.y;
            float pnew = D * xg;         // only on-chain op after the dot
            if (t < seq_len) { p = pnew; C += en0 + logD0prev; }
            // publish p_t, immediately issue step-(t+1) reads (off-chain)
            pexch[lane] = p;
#pragma unroll
            for (int k = 0; k < 32; ++k) Lp[k] = *(const float2*)&pexch[2 * k];
            // off-chain prep for next step
            float D0 = readlane0_f(D);
            logD0prev = __logf(D0);
            float gn = __fdividef(1.f, D0);
            en0 = readlane0_f(e_f);
            xg = __expf(e_f - en0) * gn;
        }
        float rs = p;
#pragma unroll
        for (int m = 32; m; m >>= 1) rs += __shfl_xor(rs, m, 64);
        float log_norm = C + __logf(rs);

        // ---------------- sequence score ----------------
        float sc = 0.f;
#pragma unroll
        for (int k = 0; k < 4; ++k) {
            int t = lane + k * 64;
            if (t < seq_len) {
                int tg = target[b * T_ + t];
                sc += ebuf[t * K_ + tg];
                if (t >= 1) sc += trans[target[b * T_ + t - 1] * K_ + tg];
            }
        }
#pragma unroll
        for (int m = 32; m; m >>= 1) sc += __shfl_xor(sc, m, 64);
        if (lane == 0) out[BT_ + b] = sc - log_norm;
    } else {
        // ================= Viterbi (wave 1): packed max-plus ================
        // Tp[k] = (trans[2k][lane], trans[2k+1][lane])
        float2 Tp[32];
#pragma unroll
        for (int k = 0; k < 32; ++k)
            Tp[k] = make_float2(trans[(2 * k) * K_ + lane],
                                trans[(2 * k + 1) * K_ + lane]);
        for (int idx = lane; idx < K_ * K_; idx += 64)
            tbuf[(idx >> 6) * 65 + (idx & 63)] = trans[idx];

        float v = ebuf[lane];
        vbuf[lane] = v;                  // history write == exchange publish
        float2 Lv[32];
#pragma unroll
        for (int k = 0; k < 32; ++k) Lv[k] = *(const float2*)&vbuf[2 * k];
        float e_n = ebuf[K_ + lane];

        for (int t = 1; t < T_; ++t) {
            float e_f = (t < T_ - 1) ? ebuf[(t + 1) * K_ + lane] : 0.f;
            float m0 = -3.4e38f, m1 = -3.4e38f, m2 = -3.4e38f, m3 = -3.4e38f;
#pragma unroll
            for (int k = 0; k < 32; k += 4) {
                float2 s0 = pk_add2(Lv[k + 0], Tp[k + 0]);
                float2 s1 = pk_add2(Lv[k + 1], Tp[k + 1]);
                float2 s2 = pk_add2(Lv[k + 2], Tp[k + 2]);
                float2 s3 = pk_add2(Lv[k + 3], Tp[k + 3]);
                m0 = fmaxf(fmaxf(m0, s0.x), s0.y);   // v_max3_f32
                m1 = fmaxf(fmaxf(m1, s1.x), s1.y);
                m2 = fmaxf(fmaxf(m2, s2.x), s2.y);
                m3 = fmaxf(fmaxf(m3, s3.x), s3.y);
            }
            float M = fmaxf(fmaxf(m0, m1), fmaxf(m2, m3));
            float vn = M + e_n;
            if (t < seq_len) v = vn;
            // publish row t (history AND exchange), issue step-(t+1) reads
            vbuf[t * K_ + lane] = v;
            const float* vrow = &vbuf[t * K_];
#pragma unroll
            for (int k = 0; k < 32; ++k) Lv[k] = *(const float2*)&vrow[2 * k];
            e_n = e_f;
        }

        // last tag: first index of max over lanes (np.argmax tie rule)
        float M = wave_max64(v);
        unsigned long long ball = __ballot(v >= M);
        int tag = (int)__builtin_ctzll(ball);

        int path[4];
#pragma unroll
        for (int k = 0; k < 4; ++k) path[k] = 0;
        if (lane == ((T_ - 1) & 63)) path[(T_ - 1) >> 6] = tag;

        float vpre = vbuf[(T_ - 2) * K_ + lane];
        for (int t = T_ - 1; t >= 1; --t) {
            float vnext = (t >= 2) ? vbuf[(t - 2) * K_ + lane] : 0.f;
            if (t < seq_len) {
                float s = vpre + tbuf[lane * 65 + tag];
                float Ms = wave_max64(s);
                unsigned long long bl = __ballot(s >= Ms);
                tag = (int)__builtin_ctzll(bl);
            }
            int pidx = t - 1;
            if (lane == (pidx & 63)) path[pidx >> 6] = tag;
            vpre = vnext;
        }
#pragma unroll
        for (int k = 0; k < 4; ++k) {
            int t = lane + k * 64;
            out[b * T_ + t] = (t < seq_len) ? (float)path[k] : 0.f;
        }
    }
}

// ---------------------------------------------------------------------------
extern "C" void kernel_launch(void* const* d_in, const int* in_sizes, int n_in,
                              void* d_out, int out_size, void* d_ws, size_t ws_size,
                              hipStream_t stream) {
    const float* hidden = (const float*)d_in[0];
    const int* masks    = (const int*)d_in[1];
    const int* target   = (const int*)d_in[2];
    const float* W      = (const float*)d_in[3];
    const float* bias   = (const float*)d_in[4];
    const float* trans  = (const float*)d_in[5];
    float* out = (float*)d_out;
    float* emis = (float*)d_ws;

    gemm_emis<<<dim3(BT_ / BM_), dim3(256), 0, stream>>>(hidden, W, bias, emis);
    crf_kernel<<<dim3(B_), dim3(128), 0, stream>>>(emis, masks, target, trans, out);
}